// Round 11
// baseline (554.929 us; speedup 1.0000x reference)
//
#include <hip/hip_runtime.h>
#include <math.h>

#define N_NODES 100000
#define N_EDGES 600000
#define N_GRAPHS 512
#define D 128
#define SCAN_BS 1024
#define SCAN_NBC ((N_NODES + SCAN_BS - 1) / SCAN_BS)   // 98

typedef unsigned short u16;
typedef __attribute__((ext_vector_type(8))) short short8;
typedef __attribute__((ext_vector_type(4))) float f32x4;
typedef __attribute__((ext_vector_type(4))) unsigned int u32x4;

__device__ __forceinline__ u16 f2bf(float f) {
    unsigned int u = __float_as_uint(f);
    u += 0x7FFFu + ((u >> 16) & 1u);
    return (u16)(u >> 16);
}
__device__ __forceinline__ float bf2f(u16 h) {
    return __uint_as_float(((unsigned int)h) << 16);
}
// packed element: hi bf16 in top 16 bits, lo bf16 in low 16 bits
__device__ __forceinline__ unsigned int packsplit(float v) {
    unsigned int u = __float_as_uint(v);
    unsigned int hi = (u + (0x7FFFu + ((u >> 16) & 1u))) & 0xffff0000u;
    float lo = v - __uint_as_float(hi);
    unsigned int ul = __float_as_uint(lo);
    unsigned int l16 = (ul + (0x7FFFu + ((ul >> 16) & 1u))) >> 16;
    return hi | l16;
}
__device__ __forceinline__ float hi_f(unsigned int w) { return __uint_as_float(w & 0xffff0000u); }
__device__ __forceinline__ float lo_f(unsigned int w) { return __uint_as_float(w << 16); }
__device__ __forceinline__ float unpack_sum(unsigned int w) { return hi_f(w) + lo_f(w); }
// fp32 -> (hi bf16 bits, lo bf16 bits) in low 16 of each
__device__ __forceinline__ void split2(float f, unsigned int& h16, unsigned int& l16) {
    unsigned int u = __float_as_uint(f);
    unsigned int hb = (u + (0x7FFFu + ((u >> 16) & 1u))) & 0xffff0000u;
    float lo = f - __uint_as_float(hb);
    unsigned int ul = __float_as_uint(lo);
    h16 = hb >> 16;
    l16 = (ul + (0x7FFFu + ((ul >> 16) & 1u))) >> 16;
}

// ---------------- zero helper ----------------
__global__ __launch_bounds__(256) void zero_i_kernel(int* __restrict__ p, int n) {
    int i = blockIdx.x * 256 + threadIdx.x;
    if (i < n) p[i] = 0;
}

// ---------------- CSR build ----------------
__global__ __launch_bounds__(256) void hist_kernel(const int* __restrict__ dst,
                                                   int* __restrict__ deg) {
    int e = blockIdx.x * 256 + threadIdx.x;
    if (e < N_EDGES) atomicAdd(&deg[dst[e]], 1);
}

__global__ __launch_bounds__(1024) void scan1_kernel(const int* __restrict__ deg,
                                                     int* __restrict__ excl,
                                                     int* __restrict__ blocksum) {
    __shared__ int buf[2][SCAN_BS];
    const int t = threadIdx.x;
    const int gid = blockIdx.x * SCAN_BS + t;
    int v = (gid < N_NODES) ? deg[gid] : 0;
    buf[0][t] = v;
    __syncthreads();
    int pi = 0;
    for (int off = 1; off < SCAN_BS; off <<= 1) {
        int val = buf[pi][t];
        if (t >= off) val += buf[pi][t - off];
        buf[pi ^ 1][t] = val;
        pi ^= 1;
        __syncthreads();
    }
    int incl = buf[pi][t];
    if (gid < N_NODES) excl[gid] = incl - v;
    if (t == SCAN_BS - 1) blocksum[blockIdx.x] = incl;
}

// scan3 with the block-total prefix computed locally (merged scan2):
// each block scans the <=128 block sums in LDS, then adds its prefix.
__global__ __launch_bounds__(256) void scan3_kernel(const int* __restrict__ excl,
                                                    const int* __restrict__ blocksum,
                                                    int* __restrict__ rowptr) {
    __shared__ int buf[2][128];
    const int t = threadIdx.x;
    if (t < 128) buf[0][t] = (t < SCAN_NBC) ? blocksum[t] : 0;
    __syncthreads();
    int pi = 0;
    for (int off = 1; off < 128; off <<= 1) {
        if (t < 128) {
            int val = buf[pi][t];
            if (t >= off) val += buf[pi][t - off];
            buf[pi ^ 1][t] = val;
        }
        pi ^= 1;
        __syncthreads();
    }
    const int i = blockIdx.x * 256 + t;
    if (i < N_NODES) {
        const int j = i / SCAN_BS;
        const int pref = (j == 0) ? 0 : buf[pi][j - 1];   // exclusive block prefix
        rowptr[i] = excl[i] + pref;
    }
    if (i == 0) rowptr[N_NODES] = N_EDGES;
}

__global__ __launch_bounds__(256) void fill_kernel(const int* __restrict__ src,
                                                   const int* __restrict__ dst,
                                                   const int* __restrict__ rowptr,
                                                   int* __restrict__ fill,
                                                   int* __restrict__ csr_src) {
    int e = blockIdx.x * 256 + threadIdx.x;
    if (e < N_EDGES) {
        int d = dst[e];
        int pos = rowptr[d] + atomicAdd(&fill[d], 1);
        csr_src[pos] = src[e];
    }
}

// ---------------- pack W' = [Wl ; Wr] (256x128) into MFMA B-fragment layout ----------------
__global__ __launch_bounds__(64) void wprep_kernel(const float* __restrict__ Wl1, const float* __restrict__ Wr1,
                                                   const float* __restrict__ Wl2, const float* __restrict__ Wr2,
                                                   const float* __restrict__ Wl3, const float* __restrict__ Wr3,
                                                   u16* __restrict__ wph, u16* __restrict__ wpl) {
    const int layer = blockIdx.x >> 6;
    const int t = blockIdx.x & 63;
    const int lane = threadIdx.x;
    const float* Wl = (layer == 0) ? Wl1 : (layer == 1) ? Wl2 : Wl3;
    const float* Wr = (layer == 0) ? Wr1 : (layer == 1) ? Wr2 : Wr3;
    const int nt = t >> 3, kt = t & 7;
    const int n = nt * 16 + (lane & 15);
    const int k0 = kt * 32 + (lane >> 4) * 8;
    const size_t base = (size_t)layer * 32768 + (size_t)(t * 64 + lane) * 8;
    #pragma unroll
    for (int j = 0; j < 8; ++j) {
        const int k = k0 + j;
        const float w = (k < 128) ? Wl[k * 128 + n] : Wr[(k - 128) * 128 + n];
        const u16 h = f2bf(w);
        wph[base + j] = h;
        wpl[base + j] = f2bf(w - bf2f(h));
    }
}

// ---------------- aggregation: mean of neighbor rows -> packed Mx ----------------
// R5-proven layout: one wave per node, lane covers 2 cols (uint2/float2),
// 4 independent row loads in flight per iteration (s0..s3 via shfl).
// Layer 1 reads x (fp32) directly; later layers read packed Hx.
__global__ __launch_bounds__(256) void agg_kernel(const unsigned int* __restrict__ Hx,
                                                  const float* __restrict__ xf,
                                                  const int* __restrict__ rowptr,
                                                  const int* __restrict__ csr_src,
                                                  unsigned int* __restrict__ Mx) {
    const int lane = threadIdx.x & 63;
    const int node = blockIdx.x * 4 + (threadIdx.x >> 6);
    if (node >= N_NODES) return;
    const int beg = rowptr[node];
    const int end = rowptr[node + 1];
    const int co = lane * 2;
    float a0 = 0.f, a1 = 0.f;

    if (xf) {
        for (int c0 = beg; c0 < end; c0 += 64) {
            const int nv = min(64, end - c0);
            int msrc = (c0 + lane < end) ? csr_src[c0 + lane] : 0;
            int j = 0;
            for (; j + 4 <= nv; j += 4) {
                const int s0 = __shfl(msrc, j + 0);
                const int s1 = __shfl(msrc, j + 1);
                const int s2 = __shfl(msrc, j + 2);
                const int s3 = __shfl(msrc, j + 3);
                const float2 w0 = *(const float2*)(xf + (size_t)s0 * D + co);
                const float2 w1 = *(const float2*)(xf + (size_t)s1 * D + co);
                const float2 w2 = *(const float2*)(xf + (size_t)s2 * D + co);
                const float2 w3 = *(const float2*)(xf + (size_t)s3 * D + co);
                a0 += w0.x + w1.x + w2.x + w3.x;
                a1 += w0.y + w1.y + w2.y + w3.y;
            }
            for (; j < nv; ++j) {
                const int s = __shfl(msrc, j);
                const float2 w = *(const float2*)(xf + (size_t)s * D + co);
                a0 += w.x;
                a1 += w.y;
            }
        }
    } else {
        for (int c0 = beg; c0 < end; c0 += 64) {
            const int nv = min(64, end - c0);
            int msrc = (c0 + lane < end) ? csr_src[c0 + lane] : 0;
            int j = 0;
            for (; j + 4 <= nv; j += 4) {
                const int s0 = __shfl(msrc, j + 0);
                const int s1 = __shfl(msrc, j + 1);
                const int s2 = __shfl(msrc, j + 2);
                const int s3 = __shfl(msrc, j + 3);
                const uint2 w0 = *(const uint2*)(Hx + (size_t)s0 * D + co);
                const uint2 w1 = *(const uint2*)(Hx + (size_t)s1 * D + co);
                const uint2 w2 = *(const uint2*)(Hx + (size_t)s2 * D + co);
                const uint2 w3 = *(const uint2*)(Hx + (size_t)s3 * D + co);
                a0 += unpack_sum(w0.x) + unpack_sum(w1.x) + unpack_sum(w2.x) + unpack_sum(w3.x);
                a1 += unpack_sum(w0.y) + unpack_sum(w1.y) + unpack_sum(w2.y) + unpack_sum(w3.y);
            }
            for (; j < nv; ++j) {
                const int s = __shfl(msrc, j);
                const uint2 w = *(const uint2*)(Hx + (size_t)s * D + co);
                a0 += unpack_sum(w.x);
                a1 += unpack_sum(w.y);
            }
        }
    }
    const float inv = 1.0f / (float)max(end - beg, 1);
    uint2 o;
    o.x = packsplit(a0 * inv);
    o.y = packsplit(a1 * inv);
    *(uint2*)(Mx + (size_t)node * D + co) = o;
}

// ---------------- MFMA GEMM: h' = relu([M | H] @ [Wl;Wr] + b) ----------------
// 128 rows/block (8 waves x 16), N=128, K=256, bf16x3 emulation; W in two
// 64 KB LDS stages (3 barriers). When sg != nullptr (layer 3): instead of
// writing h', fuse pooling+readout: wsum[r] += v*Wro[col], shfl-reduce over
// the 16 col-lanes, one atomicAdd per (wave,row) into sg[batch[row]].
__global__ __launch_bounds__(512, 4) void gemm_kernel(const unsigned int* __restrict__ Mx,
                                                      const unsigned int* Hx,
                                                      const float* __restrict__ xroot,
                                                      const u16* __restrict__ Wph,
                                                      const u16* __restrict__ Wpl,
                                                      const float* __restrict__ bias,
                                                      unsigned int* OHx,
                                                      const int* __restrict__ batch,
                                                      const float* __restrict__ Wro,
                                                      float* sg) {
    __shared__ uint4 ldsW[4096];   // 64 KB: stage hi [0:2048) + stage lo [2048:4096)
    const int t = threadIdx.x;
    const int lane = t & 63;
    const int wv = t >> 6;                 // 0..7
    const int m0 = blockIdx.x * 128 + wv * 16;
    int rm = m0 + (lane & 15);
    if (rm >= N_NODES) rm = 0;
    const int ko = (lane >> 4) * 8;

    short8 ah[8], al[8];
    // mean half (kt 0..3) from packed Mx — loads issue first
    #pragma unroll
    for (int kt = 0; kt < 4; ++kt) {
        const unsigned int* base = Mx + (size_t)rm * D + kt * 32 + ko;
        const u32x4 p = *(const u32x4*)(base);
        const u32x4 q = *(const u32x4*)(base + 4);
        u32x4 hv, lv;
        hv.x = (p.x >> 16) | (p.y & 0xffff0000u);
        hv.y = (p.z >> 16) | (p.w & 0xffff0000u);
        hv.z = (q.x >> 16) | (q.y & 0xffff0000u);
        hv.w = (q.z >> 16) | (q.w & 0xffff0000u);
        lv.x = (p.x & 0xffffu) | (p.y << 16);
        lv.y = (p.z & 0xffffu) | (p.w << 16);
        lv.z = (q.x & 0xffffu) | (q.y << 16);
        lv.w = (q.z & 0xffffu) | (q.w << 16);
        ah[kt] = __builtin_bit_cast(short8, hv);
        al[kt] = __builtin_bit_cast(short8, lv);
    }
    // root half (kt 4..7): packed Hx, or fp32 x split in-register (layer 1)
    if (xroot) {
        #pragma unroll
        for (int kt = 0; kt < 4; ++kt) {
            const float* bx = xroot + (size_t)rm * D + kt * 32 + ko;
            const f32x4 f0 = *(const f32x4*)(bx);
            const f32x4 f1 = *(const f32x4*)(bx + 4);
            unsigned int hh[8], ll[8];
            split2(f0.x, hh[0], ll[0]); split2(f0.y, hh[1], ll[1]);
            split2(f0.z, hh[2], ll[2]); split2(f0.w, hh[3], ll[3]);
            split2(f1.x, hh[4], ll[4]); split2(f1.y, hh[5], ll[5]);
            split2(f1.z, hh[6], ll[6]); split2(f1.w, hh[7], ll[7]);
            u32x4 hv, lv;
            hv.x = hh[0] | (hh[1] << 16); hv.y = hh[2] | (hh[3] << 16);
            hv.z = hh[4] | (hh[5] << 16); hv.w = hh[6] | (hh[7] << 16);
            lv.x = ll[0] | (ll[1] << 16); lv.y = ll[2] | (ll[3] << 16);
            lv.z = ll[4] | (ll[5] << 16); lv.w = ll[6] | (ll[7] << 16);
            ah[4 + kt] = __builtin_bit_cast(short8, hv);
            al[4 + kt] = __builtin_bit_cast(short8, lv);
        }
    } else {
        #pragma unroll
        for (int kt = 0; kt < 4; ++kt) {
            const unsigned int* base = Hx + (size_t)rm * D + kt * 32 + ko;
            const u32x4 p = *(const u32x4*)(base);
            const u32x4 q = *(const u32x4*)(base + 4);
            u32x4 hv, lv;
            hv.x = (p.x >> 16) | (p.y & 0xffff0000u);
            hv.y = (p.z >> 16) | (p.w & 0xffff0000u);
            hv.z = (q.x >> 16) | (q.y & 0xffff0000u);
            hv.w = (q.z >> 16) | (q.w & 0xffff0000u);
            lv.x = (p.x & 0xffffu) | (p.y << 16);
            lv.y = (p.z & 0xffffu) | (p.w << 16);
            lv.z = (q.x & 0xffffu) | (q.y << 16);
            lv.w = (q.z & 0xffffu) | (q.w << 16);
            ah[4 + kt] = __builtin_bit_cast(short8, hv);
            al[4 + kt] = __builtin_bit_cast(short8, lv);
        }
    }

    const int rowb = m0 + ((lane >> 4) << 2);
    const int cl = lane & 15;
    const u16* ldsU = (const u16*)ldsW;
    float wsum[4] = {0.f, 0.f, 0.f, 0.f};

    #pragma unroll
    for (int s = 0; s < 2; ++s) {
        if (s) __syncthreads();   // all reads of previous stage done
        {
            const uint4* gh = (const uint4*)Wph + s * 2048;
            const uint4* gl = (const uint4*)Wpl + s * 2048;
            #pragma unroll
            for (int i = 0; i < 4; ++i) {
                ldsW[t + 512 * i]        = gh[t + 512 * i];
                ldsW[2048 + t + 512 * i] = gl[t + 512 * i];
            }
        }
        __syncthreads();

        #pragma unroll
        for (int nt2 = 0; nt2 < 4; ++nt2) {
            f32x4 accP = {0.f, 0.f, 0.f, 0.f};
            f32x4 accQ = {0.f, 0.f, 0.f, 0.f};
            #pragma unroll
            for (int kt = 0; kt < 8; ++kt) {
                const int fo = (nt2 * 8 + kt) * 512 + lane * 8;
                const short8 bh = *(const short8*)(ldsU + fo);
                const short8 bl = *(const short8*)(ldsU + 16384 + fo);
                accP = __builtin_amdgcn_mfma_f32_16x16x32_bf16(ah[kt], bh, accP, 0, 0, 0);
                accQ = __builtin_amdgcn_mfma_f32_16x16x32_bf16(al[kt], bh, accQ, 0, 0, 0);
                accQ = __builtin_amdgcn_mfma_f32_16x16x32_bf16(ah[kt], bl, accQ, 0, 0, 0);
            }
            const int col = (s * 4 + nt2) * 16 + cl;
            const float bv = bias[col];
            const float wroc = sg ? Wro[col] : 0.f;
            #pragma unroll
            for (int r = 0; r < 4; ++r) {
                const int row = rowb + r;
                const float v = fmaxf(accP[r] + accQ[r] + bv, 0.f);
                if (sg) {
                    if (row < N_NODES) wsum[r] = fmaf(v, wroc, wsum[r]);
                } else if (row < N_NODES) {
                    OHx[(size_t)row * D + col] = packsplit(v);
                }
            }
        }
    }

    if (sg) {
        #pragma unroll
        for (int r = 0; r < 4; ++r) {
            float tsum = wsum[r];
            tsum += __shfl_down(tsum, 8, 64);
            tsum += __shfl_down(tsum, 4, 64);
            tsum += __shfl_down(tsum, 2, 64);
            tsum += __shfl_down(tsum, 1, 64);
            const int row = rowb + r;
            if (cl == 0 && row < N_NODES) {
                atomicAdd(&sg[batch[row]], tsum);
            }
        }
    }
}

// ---------------- final: sigmoid(sg + bro) ----------------
__global__ __launch_bounds__(256) void final_sigmoid_kernel(const float* __restrict__ sg,
                                                            const float* __restrict__ bro,
                                                            float* __restrict__ out) {
    const int g = blockIdx.x * 256 + threadIdx.x;
    if (g < N_GRAPHS) out[g] = 1.0f / (1.0f + expf(-(sg[g] + bro[0])));
}

extern "C" void kernel_launch(void* const* d_in, const int* in_sizes, int n_in,
                              void* d_out, int out_size, void* d_ws, size_t ws_size,
                              hipStream_t stream) {
    const float* x     = (const float*)d_in[0];
    const int*   ei    = (const int*)d_in[1];
    const int*   batch = (const int*)d_in[2];
    const int*   src   = ei;
    const int*   dst   = ei + N_EDGES;
    const float* Wl[3] = {(const float*)d_in[3], (const float*)d_in[6], (const float*)d_in[9]};
    const float* Wr[3] = {(const float*)d_in[4], (const float*)d_in[7], (const float*)d_in[10]};
    const float* bs[3] = {(const float*)d_in[5], (const float*)d_in[8], (const float*)d_in[11]};
    const float* Wro   = (const float*)d_in[12];
    const float* bro   = (const float*)d_in[13];
    float* out = (float*)d_out;

    const size_t ND = (size_t)N_NODES * D;
    char* ws = (char*)d_ws;
    unsigned int* Hx = (unsigned int*)ws;          // ND u32 (packed hi/lo)
    unsigned int* Mx = Hx + ND;                    // ND u32
    u16* Wph = (u16*)(Mx + ND);                    // 3*32768 u16
    u16* Wpl = Wph + 3 * 32768;                    // 3*32768 u16
    int* deg      = (int*)(Wpl + 3 * 32768);       // N  (deg, fill, sg zeroed together)
    int* fill     = deg + N_NODES;                 // N
    float* sg     = (float*)(fill + N_NODES);      // 512
    int* excl     = (int*)(sg + N_GRAPHS);         // N
    int* blocksum = excl + N_NODES;                // 128
    int* rowptr   = blocksum + 128;                // N+1
    int* csr_src  = rowptr + N_NODES + 1;          // E

    const int EB      = (N_EDGES + 255) / 256;
    const int NB      = (N_NODES + 255) / 256;
    const int NBZ     = (2 * N_NODES + N_GRAPHS + 255) / 256;
    const int AGG_B   = N_NODES / 4;                         // 25000
    const int GEMM_B  = (N_NODES + 127) / 128;               // 782

    // ---- CSR build (+ zero sg for the fused layer-3 pooling) ----
    zero_i_kernel<<<NBZ, 256, 0, stream>>>(deg, 2 * N_NODES + N_GRAPHS);
    hist_kernel<<<EB, 256, 0, stream>>>(dst, deg);
    scan1_kernel<<<SCAN_NBC, SCAN_BS, 0, stream>>>(deg, excl, blocksum);
    scan3_kernel<<<NB, 256, 0, stream>>>(excl, blocksum, rowptr);
    fill_kernel<<<EB, 256, 0, stream>>>(src, dst, rowptr, fill, csr_src);

    // ---- prep: pack weights ----
    wprep_kernel<<<192, 64, 0, stream>>>(Wl[0], Wr[0], Wl[1], Wr[1], Wl[2], Wr[2], Wph, Wpl);

    // ---- 3 layers: aggregate-then-GEMM; layer 3 fuses pooling+readout ----
    for (int l = 0; l < 3; ++l) {
        const float* xl = (l == 0) ? x : (const float*)nullptr;
        float* sgl = (l == 2) ? sg : (float*)nullptr;
        agg_kernel<<<AGG_B, 256, 0, stream>>>(Hx, xl, rowptr, csr_src, Mx);
        gemm_kernel<<<GEMM_B, 512, 0, stream>>>(Mx, Hx, xl,
                                                Wph + l * 32768, Wpl + l * 32768, bs[l],
                                                Hx, batch, Wro, sgl);
    }

    // ---- sigmoid readout ----
    final_sigmoid_kernel<<<(N_GRAPHS + 255) / 256, 256, 0, stream>>>(sg, bro, out);
}

// Round 12
// 443.579 us; speedup vs baseline: 1.2510x; 1.2510x over previous
//
#include <hip/hip_runtime.h>
#include <math.h>

#define N_NODES 100000
#define N_EDGES 600000
#define N_GRAPHS 512
#define D 128
#define SCAN_BS 1024
#define SCAN_NBC ((N_NODES + SCAN_BS - 1) / SCAN_BS)   // 98

typedef unsigned short u16;
typedef __attribute__((ext_vector_type(8))) short short8;
typedef __attribute__((ext_vector_type(4))) float f32x4;
typedef __attribute__((ext_vector_type(4))) unsigned int u32x4;

__device__ __forceinline__ u16 f2bf(float f) {
    unsigned int u = __float_as_uint(f);
    u += 0x7FFFu + ((u >> 16) & 1u);
    return (u16)(u >> 16);
}
__device__ __forceinline__ float bf2f(u16 h) {
    return __uint_as_float(((unsigned int)h) << 16);
}
// packed element: hi bf16 in top 16 bits, lo bf16 in low 16 bits
__device__ __forceinline__ unsigned int packsplit(float v) {
    unsigned int u = __float_as_uint(v);
    unsigned int hi = (u + (0x7FFFu + ((u >> 16) & 1u))) & 0xffff0000u;
    float lo = v - __uint_as_float(hi);
    unsigned int ul = __float_as_uint(lo);
    unsigned int l16 = (ul + (0x7FFFu + ((ul >> 16) & 1u))) >> 16;
    return hi | l16;
}
__device__ __forceinline__ float hi_f(unsigned int w) { return __uint_as_float(w & 0xffff0000u); }
__device__ __forceinline__ float lo_f(unsigned int w) { return __uint_as_float(w << 16); }
__device__ __forceinline__ float unpack_sum(unsigned int w) { return hi_f(w) + lo_f(w); }
// fp32 -> (hi bf16 bits, lo bf16 bits) in low 16 of each
__device__ __forceinline__ void split2(float f, unsigned int& h16, unsigned int& l16) {
    unsigned int u = __float_as_uint(f);
    unsigned int hb = (u + (0x7FFFu + ((u >> 16) & 1u))) & 0xffff0000u;
    float lo = f - __uint_as_float(hb);
    unsigned int ul = __float_as_uint(lo);
    h16 = hb >> 16;
    l16 = (ul + (0x7FFFu + ((ul >> 16) & 1u))) >> 16;
}

// ---------------- zero helper ----------------
__global__ __launch_bounds__(256) void zero_i_kernel(int* __restrict__ p, int n) {
    int i = blockIdx.x * 256 + threadIdx.x;
    if (i < n) p[i] = 0;
}

// ---------------- CSR build ----------------
__global__ __launch_bounds__(256) void hist_kernel(const int* __restrict__ dst,
                                                   int* __restrict__ deg) {
    int e = blockIdx.x * 256 + threadIdx.x;
    if (e < N_EDGES) atomicAdd(&deg[dst[e]], 1);
}

__global__ __launch_bounds__(1024) void scan1_kernel(const int* __restrict__ deg,
                                                     int* __restrict__ excl,
                                                     int* __restrict__ blocksum) {
    __shared__ int buf[2][SCAN_BS];
    const int t = threadIdx.x;
    const int gid = blockIdx.x * SCAN_BS + t;
    int v = (gid < N_NODES) ? deg[gid] : 0;
    buf[0][t] = v;
    __syncthreads();
    int pi = 0;
    for (int off = 1; off < SCAN_BS; off <<= 1) {
        int val = buf[pi][t];
        if (t >= off) val += buf[pi][t - off];
        buf[pi ^ 1][t] = val;
        pi ^= 1;
        __syncthreads();
    }
    int incl = buf[pi][t];
    if (gid < N_NODES) excl[gid] = incl - v;
    if (t == SCAN_BS - 1) blocksum[blockIdx.x] = incl;
}

// scan3 with the block-total prefix computed locally (merged scan2):
// each block scans the <=128 block sums in LDS, then adds its prefix.
__global__ __launch_bounds__(256) void scan3_kernel(const int* __restrict__ excl,
                                                    const int* __restrict__ blocksum,
                                                    int* __restrict__ rowptr) {
    __shared__ int buf[2][128];
    const int t = threadIdx.x;
    if (t < 128) buf[0][t] = (t < SCAN_NBC) ? blocksum[t] : 0;
    __syncthreads();
    int pi = 0;
    for (int off = 1; off < 128; off <<= 1) {
        if (t < 128) {
            int val = buf[pi][t];
            if (t >= off) val += buf[pi][t - off];
            buf[pi ^ 1][t] = val;
        }
        pi ^= 1;
        __syncthreads();
    }
    const int i = blockIdx.x * 256 + t;
    if (i < N_NODES) {
        const int j = i / SCAN_BS;
        const int pref = (j == 0) ? 0 : buf[pi][j - 1];   // exclusive block prefix
        rowptr[i] = excl[i] + pref;
    }
    if (i == 0) rowptr[N_NODES] = N_EDGES;
}

__global__ __launch_bounds__(256) void fill_kernel(const int* __restrict__ src,
                                                   const int* __restrict__ dst,
                                                   const int* __restrict__ rowptr,
                                                   int* __restrict__ fill,
                                                   int* __restrict__ csr_src) {
    int e = blockIdx.x * 256 + threadIdx.x;
    if (e < N_EDGES) {
        int d = dst[e];
        int pos = rowptr[d] + atomicAdd(&fill[d], 1);
        csr_src[pos] = src[e];
    }
}

// ---------------- pack W' = [Wl ; Wr] (256x128) into MFMA B-fragment layout ----------------
__global__ __launch_bounds__(64) void wprep_kernel(const float* __restrict__ Wl1, const float* __restrict__ Wr1,
                                                   const float* __restrict__ Wl2, const float* __restrict__ Wr2,
                                                   const float* __restrict__ Wl3, const float* __restrict__ Wr3,
                                                   u16* __restrict__ wph, u16* __restrict__ wpl) {
    const int layer = blockIdx.x >> 6;
    const int t = blockIdx.x & 63;
    const int lane = threadIdx.x;
    const float* Wl = (layer == 0) ? Wl1 : (layer == 1) ? Wl2 : Wl3;
    const float* Wr = (layer == 0) ? Wr1 : (layer == 1) ? Wr2 : Wr3;
    const int nt = t >> 3, kt = t & 7;
    const int n = nt * 16 + (lane & 15);
    const int k0 = kt * 32 + (lane >> 4) * 8;
    const size_t base = (size_t)layer * 32768 + (size_t)(t * 64 + lane) * 8;
    #pragma unroll
    for (int j = 0; j < 8; ++j) {
        const int k = k0 + j;
        const float w = (k < 128) ? Wl[k * 128 + n] : Wr[(k - 128) * 128 + n];
        const u16 h = f2bf(w);
        wph[base + j] = h;
        wpl[base + j] = f2bf(w - bf2f(h));
    }
}

// ---------------- aggregation: mean of neighbor rows -> packed Mx ----------------
// one wave per node, lane covers 2 cols; 4 independent row loads in flight.
// Layer 1 reads x (fp32) directly; later layers read packed Hx.
__global__ __launch_bounds__(256) void agg_kernel(const unsigned int* __restrict__ Hx,
                                                  const float* __restrict__ xf,
                                                  const int* __restrict__ rowptr,
                                                  const int* __restrict__ csr_src,
                                                  unsigned int* __restrict__ Mx) {
    const int lane = threadIdx.x & 63;
    const int node = blockIdx.x * 4 + (threadIdx.x >> 6);
    if (node >= N_NODES) return;
    const int beg = rowptr[node];
    const int end = rowptr[node + 1];
    const int co = lane * 2;
    float a0 = 0.f, a1 = 0.f;

    if (xf) {
        for (int c0 = beg; c0 < end; c0 += 64) {
            const int nv = min(64, end - c0);
            int msrc = (c0 + lane < end) ? csr_src[c0 + lane] : 0;
            int j = 0;
            for (; j + 4 <= nv; j += 4) {
                const int s0 = __shfl(msrc, j + 0);
                const int s1 = __shfl(msrc, j + 1);
                const int s2 = __shfl(msrc, j + 2);
                const int s3 = __shfl(msrc, j + 3);
                const float2 w0 = *(const float2*)(xf + (size_t)s0 * D + co);
                const float2 w1 = *(const float2*)(xf + (size_t)s1 * D + co);
                const float2 w2 = *(const float2*)(xf + (size_t)s2 * D + co);
                const float2 w3 = *(const float2*)(xf + (size_t)s3 * D + co);
                a0 += w0.x + w1.x + w2.x + w3.x;
                a1 += w0.y + w1.y + w2.y + w3.y;
            }
            for (; j < nv; ++j) {
                const int s = __shfl(msrc, j);
                const float2 w = *(const float2*)(xf + (size_t)s * D + co);
                a0 += w.x;
                a1 += w.y;
            }
        }
    } else {
        for (int c0 = beg; c0 < end; c0 += 64) {
            const int nv = min(64, end - c0);
            int msrc = (c0 + lane < end) ? csr_src[c0 + lane] : 0;
            int j = 0;
            for (; j + 4 <= nv; j += 4) {
                const int s0 = __shfl(msrc, j + 0);
                const int s1 = __shfl(msrc, j + 1);
                const int s2 = __shfl(msrc, j + 2);
                const int s3 = __shfl(msrc, j + 3);
                const uint2 w0 = *(const uint2*)(Hx + (size_t)s0 * D + co);
                const uint2 w1 = *(const uint2*)(Hx + (size_t)s1 * D + co);
                const uint2 w2 = *(const uint2*)(Hx + (size_t)s2 * D + co);
                const uint2 w3 = *(const uint2*)(Hx + (size_t)s3 * D + co);
                a0 += unpack_sum(w0.x) + unpack_sum(w1.x) + unpack_sum(w2.x) + unpack_sum(w3.x);
                a1 += unpack_sum(w0.y) + unpack_sum(w1.y) + unpack_sum(w2.y) + unpack_sum(w3.y);
            }
            for (; j < nv; ++j) {
                const int s = __shfl(msrc, j);
                const uint2 w = *(const uint2*)(Hx + (size_t)s * D + co);
                a0 += unpack_sum(w.x);
                a1 += unpack_sum(w.y);
            }
        }
    }
    const float inv = 1.0f / (float)max(end - beg, 1);
    uint2 o;
    o.x = packsplit(a0 * inv);
    o.y = packsplit(a1 * inv);
    *(uint2*)(Mx + (size_t)node * D + co) = o;
}

// ---------------- MFMA GEMM: h' = relu([M | H] @ [Wl;Wr] + b) ----------------
// 128 rows/block (8 waves x 16), N=128, K=256, bf16x3 emulation; W in two
// 64 KB LDS stages (3 barriers). When rowdot != nullptr (layer 3): instead of
// writing h', compute rowdot[row] = sum_col relu(.)*Wro[col] via 16-lane shfl
// reduce and ONE plain store per row (no atomics, 0.4 MB total write).
__global__ __launch_bounds__(512, 4) void gemm_kernel(const unsigned int* __restrict__ Mx,
                                                      const unsigned int* Hx,
                                                      const float* __restrict__ xroot,
                                                      const u16* __restrict__ Wph,
                                                      const u16* __restrict__ Wpl,
                                                      const float* __restrict__ bias,
                                                      unsigned int* OHx,
                                                      const float* __restrict__ Wro,
                                                      float* rowdot) {
    __shared__ uint4 ldsW[4096];   // 64 KB: stage hi [0:2048) + stage lo [2048:4096)
    const int t = threadIdx.x;
    const int lane = t & 63;
    const int wv = t >> 6;                 // 0..7
    const int m0 = blockIdx.x * 128 + wv * 16;
    int rm = m0 + (lane & 15);
    if (rm >= N_NODES) rm = 0;
    const int ko = (lane >> 4) * 8;

    short8 ah[8], al[8];
    // mean half (kt 0..3) from packed Mx — loads issue first
    #pragma unroll
    for (int kt = 0; kt < 4; ++kt) {
        const unsigned int* base = Mx + (size_t)rm * D + kt * 32 + ko;
        const u32x4 p = *(const u32x4*)(base);
        const u32x4 q = *(const u32x4*)(base + 4);
        u32x4 hv, lv;
        hv.x = (p.x >> 16) | (p.y & 0xffff0000u);
        hv.y = (p.z >> 16) | (p.w & 0xffff0000u);
        hv.z = (q.x >> 16) | (q.y & 0xffff0000u);
        hv.w = (q.z >> 16) | (q.w & 0xffff0000u);
        lv.x = (p.x & 0xffffu) | (p.y << 16);
        lv.y = (p.z & 0xffffu) | (p.w << 16);
        lv.z = (q.x & 0xffffu) | (q.y << 16);
        lv.w = (q.z & 0xffffu) | (q.w << 16);
        ah[kt] = __builtin_bit_cast(short8, hv);
        al[kt] = __builtin_bit_cast(short8, lv);
    }
    // root half (kt 4..7): packed Hx, or fp32 x split in-register (layer 1)
    if (xroot) {
        #pragma unroll
        for (int kt = 0; kt < 4; ++kt) {
            const float* bx = xroot + (size_t)rm * D + kt * 32 + ko;
            const f32x4 f0 = *(const f32x4*)(bx);
            const f32x4 f1 = *(const f32x4*)(bx + 4);
            unsigned int hh[8], ll[8];
            split2(f0.x, hh[0], ll[0]); split2(f0.y, hh[1], ll[1]);
            split2(f0.z, hh[2], ll[2]); split2(f0.w, hh[3], ll[3]);
            split2(f1.x, hh[4], ll[4]); split2(f1.y, hh[5], ll[5]);
            split2(f1.z, hh[6], ll[6]); split2(f1.w, hh[7], ll[7]);
            u32x4 hv, lv;
            hv.x = hh[0] | (hh[1] << 16); hv.y = hh[2] | (hh[3] << 16);
            hv.z = hh[4] | (hh[5] << 16); hv.w = hh[6] | (hh[7] << 16);
            lv.x = ll[0] | (ll[1] << 16); lv.y = ll[2] | (ll[3] << 16);
            lv.z = ll[4] | (ll[5] << 16); lv.w = ll[6] | (ll[7] << 16);
            ah[4 + kt] = __builtin_bit_cast(short8, hv);
            al[4 + kt] = __builtin_bit_cast(short8, lv);
        }
    } else {
        #pragma unroll
        for (int kt = 0; kt < 4; ++kt) {
            const unsigned int* base = Hx + (size_t)rm * D + kt * 32 + ko;
            const u32x4 p = *(const u32x4*)(base);
            const u32x4 q = *(const u32x4*)(base + 4);
            u32x4 hv, lv;
            hv.x = (p.x >> 16) | (p.y & 0xffff0000u);
            hv.y = (p.z >> 16) | (p.w & 0xffff0000u);
            hv.z = (q.x >> 16) | (q.y & 0xffff0000u);
            hv.w = (q.z >> 16) | (q.w & 0xffff0000u);
            lv.x = (p.x & 0xffffu) | (p.y << 16);
            lv.y = (p.z & 0xffffu) | (p.w << 16);
            lv.z = (q.x & 0xffffu) | (q.y << 16);
            lv.w = (q.z & 0xffffu) | (q.w << 16);
            ah[4 + kt] = __builtin_bit_cast(short8, hv);
            al[4 + kt] = __builtin_bit_cast(short8, lv);
        }
    }

    const int rowb = m0 + ((lane >> 4) << 2);
    const int cl = lane & 15;
    const u16* ldsU = (const u16*)ldsW;
    float wsum[4] = {0.f, 0.f, 0.f, 0.f};

    #pragma unroll
    for (int s = 0; s < 2; ++s) {
        if (s) __syncthreads();   // all reads of previous stage done
        {
            const uint4* gh = (const uint4*)Wph + s * 2048;
            const uint4* gl = (const uint4*)Wpl + s * 2048;
            #pragma unroll
            for (int i = 0; i < 4; ++i) {
                ldsW[t + 512 * i]        = gh[t + 512 * i];
                ldsW[2048 + t + 512 * i] = gl[t + 512 * i];
            }
        }
        __syncthreads();

        #pragma unroll
        for (int nt2 = 0; nt2 < 4; ++nt2) {
            f32x4 accP = {0.f, 0.f, 0.f, 0.f};
            f32x4 accQ = {0.f, 0.f, 0.f, 0.f};
            #pragma unroll
            for (int kt = 0; kt < 8; ++kt) {
                const int fo = (nt2 * 8 + kt) * 512 + lane * 8;
                const short8 bh = *(const short8*)(ldsU + fo);
                const short8 bl = *(const short8*)(ldsU + 16384 + fo);
                accP = __builtin_amdgcn_mfma_f32_16x16x32_bf16(ah[kt], bh, accP, 0, 0, 0);
                accQ = __builtin_amdgcn_mfma_f32_16x16x32_bf16(al[kt], bh, accQ, 0, 0, 0);
                accQ = __builtin_amdgcn_mfma_f32_16x16x32_bf16(ah[kt], bl, accQ, 0, 0, 0);
            }
            const int col = (s * 4 + nt2) * 16 + cl;
            const float bv = bias[col];
            const float wroc = rowdot ? Wro[col] : 0.f;
            #pragma unroll
            for (int r = 0; r < 4; ++r) {
                const int row = rowb + r;
                const float v = fmaxf(accP[r] + accQ[r] + bv, 0.f);
                if (rowdot) {
                    wsum[r] = fmaf(v, wroc, wsum[r]);
                } else if (row < N_NODES) {
                    OHx[(size_t)row * D + col] = packsplit(v);
                }
            }
        }
    }

    if (rowdot) {
        #pragma unroll
        for (int r = 0; r < 4; ++r) {
            float tsum = wsum[r];
            tsum += __shfl_down(tsum, 8, 64);
            tsum += __shfl_down(tsum, 4, 64);
            tsum += __shfl_down(tsum, 2, 64);
            tsum += __shfl_down(tsum, 1, 64);
            const int row = rowb + r;
            if (cl == 0 && row < N_NODES) {
                rowdot[row] = tsum;   // plain store, row owned by this wave
            }
        }
    }
}

// ---------------- final: per-graph sum of rowdot + sigmoid (batch sorted) ----------------
__global__ __launch_bounds__(64) void final_kernel(const float* __restrict__ rowdot,
                                                   const int* __restrict__ batch,
                                                   const float* __restrict__ bro,
                                                   float* __restrict__ out) {
    const int g = blockIdx.x;
    const int t = threadIdx.x;
    int lo = 0, hi = N_NODES;
    while (lo < hi) { int mid = (lo + hi) >> 1; if (batch[mid] < g) lo = mid + 1; else hi = mid; }
    int lo2 = lo, hi2 = N_NODES;
    while (lo2 < hi2) { int mid = (lo2 + hi2) >> 1; if (batch[mid] < g + 1) lo2 = mid + 1; else hi2 = mid; }

    float acc = 0.0f;
    for (int i = lo + t; i < lo2; i += 64) acc += rowdot[i];
    #pragma unroll
    for (int off = 32; off > 0; off >>= 1) acc += __shfl_down(acc, off, 64);
    if (t == 0) out[g] = 1.0f / (1.0f + expf(-(acc + bro[0])));
}

extern "C" void kernel_launch(void* const* d_in, const int* in_sizes, int n_in,
                              void* d_out, int out_size, void* d_ws, size_t ws_size,
                              hipStream_t stream) {
    const float* x     = (const float*)d_in[0];
    const int*   ei    = (const int*)d_in[1];
    const int*   batch = (const int*)d_in[2];
    const int*   src   = ei;
    const int*   dst   = ei + N_EDGES;
    const float* Wl[3] = {(const float*)d_in[3], (const float*)d_in[6], (const float*)d_in[9]};
    const float* Wr[3] = {(const float*)d_in[4], (const float*)d_in[7], (const float*)d_in[10]};
    const float* bs[3] = {(const float*)d_in[5], (const float*)d_in[8], (const float*)d_in[11]};
    const float* Wro   = (const float*)d_in[12];
    const float* bro   = (const float*)d_in[13];
    float* out = (float*)d_out;

    const size_t ND = (size_t)N_NODES * D;
    char* ws = (char*)d_ws;
    unsigned int* Hx = (unsigned int*)ws;          // ND u32 (packed hi/lo)
    unsigned int* Mx = Hx + ND;                    // ND u32
    u16* Wph = (u16*)(Mx + ND);                    // 3*32768 u16
    u16* Wpl = Wph + 3 * 32768;                    // 3*32768 u16
    int* deg      = (int*)(Wpl + 3 * 32768);       // N (deg+fill zeroed together)
    int* fill     = deg + N_NODES;                 // N
    float* rowdot = (float*)(fill + N_NODES);      // N (fully written by layer-3 gemm)
    int* excl     = (int*)(rowdot + N_NODES);      // N
    int* blocksum = excl + N_NODES;                // 128
    int* rowptr   = blocksum + 128;                // N+1
    int* csr_src  = rowptr + N_NODES + 1;          // E

    const int EB      = (N_EDGES + 255) / 256;
    const int NB      = (N_NODES + 255) / 256;
    const int NB2     = (2 * N_NODES + 255) / 256;
    const int AGG_B   = N_NODES / 4;                         // 25000
    const int GEMM_B  = (N_NODES + 127) / 128;               // 782

    // ---- CSR build ----
    zero_i_kernel<<<NB2, 256, 0, stream>>>(deg, 2 * N_NODES);   // deg + fill
    hist_kernel<<<EB, 256, 0, stream>>>(dst, deg);
    scan1_kernel<<<SCAN_NBC, SCAN_BS, 0, stream>>>(deg, excl, blocksum);
    scan3_kernel<<<NB, 256, 0, stream>>>(excl, blocksum, rowptr);
    fill_kernel<<<EB, 256, 0, stream>>>(src, dst, rowptr, fill, csr_src);

    // ---- prep: pack weights ----
    wprep_kernel<<<192, 64, 0, stream>>>(Wl[0], Wr[0], Wl[1], Wr[1], Wl[2], Wr[2], Wph, Wpl);

    // ---- 3 layers: aggregate-then-GEMM; layer 3 fuses readout to rowdot ----
    for (int l = 0; l < 3; ++l) {
        const float* xl = (l == 0) ? x : (const float*)nullptr;
        float* rdl = (l == 2) ? rowdot : (float*)nullptr;
        agg_kernel<<<AGG_B, 256, 0, stream>>>(Hx, xl, rowptr, csr_src, Mx);
        gemm_kernel<<<GEMM_B, 512, 0, stream>>>(Mx, Hx, xl,
                                                Wph + l * 32768, Wpl + l * 32768, bs[l],
                                                Hx, Wro, rdl);
    }

    // ---- per-graph sum + sigmoid ----
    final_kernel<<<N_GRAPHS, 64, 0, stream>>>(rowdot, batch, bro, out);
}

// Round 13
// 403.236 us; speedup vs baseline: 1.3762x; 1.1000x over previous
//
#include <hip/hip_runtime.h>
#include <math.h>

#define N_NODES 100000
#define N_EDGES 600000
#define N_GRAPHS 512
#define D 128
#define SCAN_BS 1024
#define SCAN_NBC ((N_NODES + SCAN_BS - 1) / SCAN_BS)   // 98

typedef unsigned short u16;
typedef __attribute__((ext_vector_type(8))) short short8;
typedef __attribute__((ext_vector_type(4))) float f32x4;

__device__ __forceinline__ u16 f2bf(float f) {
    unsigned int u = __float_as_uint(f);
    u += 0x7FFFu + ((u >> 16) & 1u);
    return (u16)(u >> 16);
}
__device__ __forceinline__ float bf2f(u16 h) {
    return __uint_as_float(((unsigned int)h) << 16);
}
// fp32 -> (hi bf16 bits, lo bf16 bits) in low 16 of each
__device__ __forceinline__ void split2(float f, unsigned int& h16, unsigned int& l16) {
    unsigned int u = __float_as_uint(f);
    unsigned int hb = (u + (0x7FFFu + ((u >> 16) & 1u))) & 0xffff0000u;
    float lo = f - __uint_as_float(hb);
    unsigned int ul = __float_as_uint(lo);
    h16 = hb >> 16;
    l16 = (ul + (0x7FFFu + ((ul >> 16) & 1u))) >> 16;
}

// ---------------- zero helper ----------------
__global__ __launch_bounds__(256) void zero_i_kernel(int* __restrict__ p, int n) {
    int i = blockIdx.x * 256 + threadIdx.x;
    if (i < n) p[i] = 0;
}

// ---------------- CSR build ----------------
__global__ __launch_bounds__(256) void hist_kernel(const int* __restrict__ dst,
                                                   int* __restrict__ deg) {
    int e = blockIdx.x * 256 + threadIdx.x;
    if (e < N_EDGES) atomicAdd(&deg[dst[e]], 1);
}

__global__ __launch_bounds__(1024) void scan1_kernel(const int* __restrict__ deg,
                                                     int* __restrict__ excl,
                                                     int* __restrict__ blocksum) {
    __shared__ int buf[2][SCAN_BS];
    const int t = threadIdx.x;
    const int gid = blockIdx.x * SCAN_BS + t;
    int v = (gid < N_NODES) ? deg[gid] : 0;
    buf[0][t] = v;
    __syncthreads();
    int pi = 0;
    for (int off = 1; off < SCAN_BS; off <<= 1) {
        int val = buf[pi][t];
        if (t >= off) val += buf[pi][t - off];
        buf[pi ^ 1][t] = val;
        pi ^= 1;
        __syncthreads();
    }
    int incl = buf[pi][t];
    if (gid < N_NODES) excl[gid] = incl - v;
    if (t == SCAN_BS - 1) blocksum[blockIdx.x] = incl;
}

// scan3 with the block-total prefix computed locally (merged scan2)
__global__ __launch_bounds__(256) void scan3_kernel(const int* __restrict__ excl,
                                                    const int* __restrict__ blocksum,
                                                    int* __restrict__ rowptr) {
    __shared__ int buf[2][128];
    const int t = threadIdx.x;
    if (t < 128) buf[0][t] = (t < SCAN_NBC) ? blocksum[t] : 0;
    __syncthreads();
    int pi = 0;
    for (int off = 1; off < 128; off <<= 1) {
        if (t < 128) {
            int val = buf[pi][t];
            if (t >= off) val += buf[pi][t - off];
            buf[pi ^ 1][t] = val;
        }
        pi ^= 1;
        __syncthreads();
    }
    const int i = blockIdx.x * 256 + t;
    if (i < N_NODES) {
        const int j = i / SCAN_BS;
        const int pref = (j == 0) ? 0 : buf[pi][j - 1];
        rowptr[i] = excl[i] + pref;
    }
    if (i == 0) rowptr[N_NODES] = N_EDGES;
}

__global__ __launch_bounds__(256) void fill_kernel(const int* __restrict__ src,
                                                   const int* __restrict__ dst,
                                                   const int* __restrict__ rowptr,
                                                   int* __restrict__ fill,
                                                   int* __restrict__ csr_src) {
    int e = blockIdx.x * 256 + threadIdx.x;
    if (e < N_EDGES) {
        int d = dst[e];
        int pos = rowptr[d] + atomicAdd(&fill[d], 1);
        csr_src[pos] = src[e];
    }
}

// ---------------- split x (fp32 -> separate bf16 hi/lo planes) ----------------
__global__ __launch_bounds__(256) void split_x_kernel(const float* __restrict__ x,
                                                      u16* __restrict__ Hhi,
                                                      u16* __restrict__ Hlo) {
    const int i = blockIdx.x * 256 + threadIdx.x;   // 4 elems/thread
    const float4 v = ((const float4*)x)[i];
    unsigned int h0, l0, h1, l1, h2, l2, h3, l3;
    split2(v.x, h0, l0); split2(v.y, h1, l1);
    split2(v.z, h2, l2); split2(v.w, h3, l3);
    uint2 oh, ol;
    oh.x = h0 | (h1 << 16); oh.y = h2 | (h3 << 16);
    ol.x = l0 | (l1 << 16); ol.y = l2 | (l3 << 16);
    ((uint2*)Hhi)[i] = oh;
    ((uint2*)Hlo)[i] = ol;
}

// ---------------- pack W' = [Wl ; Wr] (256x128) into MFMA B-fragment layout ----------------
__global__ __launch_bounds__(64) void wprep_kernel(const float* __restrict__ Wl1, const float* __restrict__ Wr1,
                                                   const float* __restrict__ Wl2, const float* __restrict__ Wr2,
                                                   const float* __restrict__ Wl3, const float* __restrict__ Wr3,
                                                   u16* __restrict__ wph, u16* __restrict__ wpl) {
    const int layer = blockIdx.x >> 6;
    const int t = blockIdx.x & 63;
    const int lane = threadIdx.x;
    const float* Wl = (layer == 0) ? Wl1 : (layer == 1) ? Wl2 : Wl3;
    const float* Wr = (layer == 0) ? Wr1 : (layer == 1) ? Wr2 : Wr3;
    const int nt = t >> 3, kt = t & 7;
    const int n = nt * 16 + (lane & 15);
    const int k0 = kt * 32 + (lane >> 4) * 8;
    const size_t base = (size_t)layer * 32768 + (size_t)(t * 64 + lane) * 8;
    #pragma unroll
    for (int j = 0; j < 8; ++j) {
        const int k = k0 + j;
        const float w = (k < 128) ? Wl[k * 128 + n] : Wr[(k - 128) * 128 + n];
        const u16 h = f2bf(w);
        wph[base + j] = h;
        wpl[base + j] = f2bf(w - bf2f(h));
    }
}

// ---------------- aggregation: mean of neighbor hi-plane rows -> bf16 Mb ----------------
// one wave per node, lane covers 2 cols (one u32 = 2 bf16); 4 independent
// row loads in flight per iteration. Gather reads ONLY the hi plane (2 B/elem).
__global__ __launch_bounds__(256) void agg_kernel(const u16* __restrict__ Hhi,
                                                  const int* __restrict__ rowptr,
                                                  const int* __restrict__ csr_src,
                                                  u16* __restrict__ Mb) {
    const int lane = threadIdx.x & 63;
    const int node = blockIdx.x * 4 + (threadIdx.x >> 6);
    if (node >= N_NODES) return;
    const int beg = rowptr[node];
    const int end = rowptr[node + 1];
    const unsigned int* H32 = (const unsigned int*)Hhi;   // row stride 64 u32
    float a0 = 0.f, a1 = 0.f;

    for (int c0 = beg; c0 < end; c0 += 64) {
        const int nv = min(64, end - c0);
        int msrc = (c0 + lane < end) ? csr_src[c0 + lane] : 0;
        int j = 0;
        for (; j + 4 <= nv; j += 4) {
            const int s0 = __shfl(msrc, j + 0);
            const int s1 = __shfl(msrc, j + 1);
            const int s2 = __shfl(msrc, j + 2);
            const int s3 = __shfl(msrc, j + 3);
            const unsigned int w0 = H32[(size_t)s0 * 64 + lane];
            const unsigned int w1 = H32[(size_t)s1 * 64 + lane];
            const unsigned int w2 = H32[(size_t)s2 * 64 + lane];
            const unsigned int w3 = H32[(size_t)s3 * 64 + lane];
            a0 += __uint_as_float(w0 << 16) + __uint_as_float(w1 << 16)
                + __uint_as_float(w2 << 16) + __uint_as_float(w3 << 16);
            a1 += __uint_as_float(w0 & 0xffff0000u) + __uint_as_float(w1 & 0xffff0000u)
                + __uint_as_float(w2 & 0xffff0000u) + __uint_as_float(w3 & 0xffff0000u);
        }
        for (; j < nv; ++j) {
            const int s = __shfl(msrc, j);
            const unsigned int w = H32[(size_t)s * 64 + lane];
            a0 += __uint_as_float(w << 16);
            a1 += __uint_as_float(w & 0xffff0000u);
        }
    }
    const float inv = 1.0f / (float)max(end - beg, 1);
    const unsigned int o = (unsigned int)f2bf(a0 * inv) | ((unsigned int)f2bf(a1 * inv) << 16);
    ((unsigned int*)Mb)[(size_t)node * 64 + lane] = o;
}

// ---------------- MFMA GEMM: h' = relu([Mb | H] @ [Wl;Wr] + b) ----------------
// 128 rows/block (8 waves x 16), K=256; W in two 64 KB LDS stages (3 barriers).
// A: mean from bf16 Mb (direct short8), root from Hhi+Hlo planes (direct
// short8, no unpack). Single fp32 accumulator; per tile: mean 2 MFMAs
// (am x bh, am x bl), root 3 MFMAs (ah x bh, ah x bl, al x bh; al x bl ~2^-18
// dropped). Layers 1-2 write h' hi/lo planes in place (per-wave rows only);
// layer 3 computes rowdot[row] = sum_col relu(.)*Wro[col] (no h' write).
__global__ __launch_bounds__(512, 4) void gemm_kernel(const u16* __restrict__ Mb,
                                                      const u16* Hhi, const u16* Hlo,
                                                      const u16* __restrict__ Wph,
                                                      const u16* __restrict__ Wpl,
                                                      const float* __restrict__ bias,
                                                      u16* OHhi, u16* OHlo,
                                                      const float* __restrict__ Wro,
                                                      float* rowdot) {
    __shared__ uint4 ldsW[4096];   // 64 KB: stage hi [0:2048) + stage lo [2048:4096)
    const int t = threadIdx.x;
    const int lane = t & 63;
    const int wv = t >> 6;
    const int m0 = blockIdx.x * 128 + wv * 16;
    int rm = m0 + (lane & 15);
    if (rm >= N_NODES) rm = 0;
    const int ko = (lane >> 4) * 8;

    // A fragments: direct 16 B loads, no unpack
    short8 am[4], ah[4], al[4];
    #pragma unroll
    for (int kt = 0; kt < 4; ++kt) {
        am[kt] = *(const short8*)(Mb  + (size_t)rm * D + kt * 32 + ko);
        ah[kt] = *(const short8*)(Hhi + (size_t)rm * D + kt * 32 + ko);
        al[kt] = *(const short8*)(Hlo + (size_t)rm * D + kt * 32 + ko);
    }

    const int rowb = m0 + ((lane >> 4) << 2);
    const int cl = lane & 15;
    const u16* ldsU = (const u16*)ldsW;
    float wsum[4] = {0.f, 0.f, 0.f, 0.f};

    #pragma unroll
    for (int s = 0; s < 2; ++s) {
        if (s) __syncthreads();
        {
            const uint4* gh = (const uint4*)Wph + s * 2048;
            const uint4* gl = (const uint4*)Wpl + s * 2048;
            #pragma unroll
            for (int i = 0; i < 4; ++i) {
                ldsW[t + 512 * i]        = gh[t + 512 * i];
                ldsW[2048 + t + 512 * i] = gl[t + 512 * i];
            }
        }
        __syncthreads();

        #pragma unroll
        for (int nt2 = 0; nt2 < 4; ++nt2) {
            f32x4 acc = {0.f, 0.f, 0.f, 0.f};
            #pragma unroll
            for (int kt = 0; kt < 8; ++kt) {
                const int fo = (nt2 * 8 + kt) * 512 + lane * 8;
                const short8 bh = *(const short8*)(ldsU + fo);
                const short8 bl = *(const short8*)(ldsU + 16384 + fo);
                if (kt < 4) {
                    acc = __builtin_amdgcn_mfma_f32_16x16x32_bf16(am[kt], bh, acc, 0, 0, 0);
                    acc = __builtin_amdgcn_mfma_f32_16x16x32_bf16(am[kt], bl, acc, 0, 0, 0);
                } else {
                    acc = __builtin_amdgcn_mfma_f32_16x16x32_bf16(ah[kt - 4], bh, acc, 0, 0, 0);
                    acc = __builtin_amdgcn_mfma_f32_16x16x32_bf16(ah[kt - 4], bl, acc, 0, 0, 0);
                    acc = __builtin_amdgcn_mfma_f32_16x16x32_bf16(al[kt - 4], bh, acc, 0, 0, 0);
                }
            }
            const int col = (s * 4 + nt2) * 16 + cl;
            const float bv = bias[col];
            const float wroc = rowdot ? Wro[col] : 0.f;
            #pragma unroll
            for (int r = 0; r < 4; ++r) {
                const int row = rowb + r;
                const float v = fmaxf(acc[r] + bv, 0.f);
                if (rowdot) {
                    wsum[r] = fmaf(v, wroc, wsum[r]);
                } else if (row < N_NODES) {
                    unsigned int h16, l16;
                    split2(v, h16, l16);
                    OHhi[(size_t)row * D + col] = (u16)h16;
                    OHlo[(size_t)row * D + col] = (u16)l16;
                }
            }
        }
    }

    if (rowdot) {
        #pragma unroll
        for (int r = 0; r < 4; ++r) {
            float tsum = wsum[r];
            tsum += __shfl_down(tsum, 8, 64);
            tsum += __shfl_down(tsum, 4, 64);
            tsum += __shfl_down(tsum, 2, 64);
            tsum += __shfl_down(tsum, 1, 64);
            const int row = rowb + r;
            if (cl == 0 && row < N_NODES) {
                rowdot[row] = tsum;   // plain store, row owned by this wave
            }
        }
    }
}

// ---------------- final: per-graph sum of rowdot + sigmoid (batch sorted) ----------------
__global__ __launch_bounds__(64) void final_kernel(const float* __restrict__ rowdot,
                                                   const int* __restrict__ batch,
                                                   const float* __restrict__ bro,
                                                   float* __restrict__ out) {
    const int g = blockIdx.x;
    const int t = threadIdx.x;
    int lo = 0, hi = N_NODES;
    while (lo < hi) { int mid = (lo + hi) >> 1; if (batch[mid] < g) lo = mid + 1; else hi = mid; }
    int lo2 = lo, hi2 = N_NODES;
    while (lo2 < hi2) { int mid = (lo2 + hi2) >> 1; if (batch[mid] < g + 1) lo2 = mid + 1; else hi2 = mid; }

    float acc = 0.0f;
    for (int i = lo + t; i < lo2; i += 64) acc += rowdot[i];
    #pragma unroll
    for (int off = 32; off > 0; off >>= 1) acc += __shfl_down(acc, off, 64);
    if (t == 0) out[g] = 1.0f / (1.0f + expf(-(acc + bro[0])));
}

extern "C" void kernel_launch(void* const* d_in, const int* in_sizes, int n_in,
                              void* d_out, int out_size, void* d_ws, size_t ws_size,
                              hipStream_t stream) {
    const float* x     = (const float*)d_in[0];
    const int*   ei    = (const int*)d_in[1];
    const int*   batch = (const int*)d_in[2];
    const int*   src   = ei;
    const int*   dst   = ei + N_EDGES;
    const float* Wl[3] = {(const float*)d_in[3], (const float*)d_in[6], (const float*)d_in[9]};
    const float* Wr[3] = {(const float*)d_in[4], (const float*)d_in[7], (const float*)d_in[10]};
    const float* bs[3] = {(const float*)d_in[5], (const float*)d_in[8], (const float*)d_in[11]};
    const float* Wro   = (const float*)d_in[12];
    const float* bro   = (const float*)d_in[13];
    float* out = (float*)d_out;

    const size_t ND = (size_t)N_NODES * D;
    char* ws = (char*)d_ws;
    u16* Hhi = (u16*)ws;                           // ND u16
    u16* Hlo = Hhi + ND;                           // ND u16
    u16* Mb  = Hlo + ND;                           // ND u16 (bf16 mean)
    u16* Wph = Mb + ND;                            // 3*32768 u16
    u16* Wpl = Wph + 3 * 32768;                    // 3*32768 u16
    int* deg      = (int*)(Wpl + 3 * 32768);       // N (deg+fill zeroed together)
    int* fill     = deg + N_NODES;                 // N
    float* rowdot = (float*)(fill + N_NODES);      // N
    int* excl     = (int*)(rowdot + N_NODES);      // N
    int* blocksum = excl + N_NODES;                // 128
    int* rowptr   = blocksum + 128;                // N+1
    int* csr_src  = rowptr + N_NODES + 1;          // E

    const int EB      = (N_EDGES + 255) / 256;
    const int NB      = (N_NODES + 255) / 256;
    const int NB2     = (2 * N_NODES + 255) / 256;
    const int SPLIT_B = (int)(ND / 4 / 256);                 // 12500
    const int AGG_B   = N_NODES / 4;                         // 25000
    const int GEMM_B  = (N_NODES + 127) / 128;               // 782

    // ---- CSR build ----
    zero_i_kernel<<<NB2, 256, 0, stream>>>(deg, 2 * N_NODES);
    hist_kernel<<<EB, 256, 0, stream>>>(dst, deg);
    scan1_kernel<<<SCAN_NBC, SCAN_BS, 0, stream>>>(deg, excl, blocksum);
    scan3_kernel<<<NB, 256, 0, stream>>>(excl, blocksum, rowptr);
    fill_kernel<<<EB, 256, 0, stream>>>(src, dst, rowptr, fill, csr_src);

    // ---- prep: split x into hi/lo planes, pack weights ----
    split_x_kernel<<<SPLIT_B, 256, 0, stream>>>(x, Hhi, Hlo);
    wprep_kernel<<<192, 64, 0, stream>>>(Wl[0], Wr[0], Wl[1], Wr[1], Wl[2], Wr[2], Wph, Wpl);

    // ---- 3 layers: aggregate (hi-plane gather) then GEMM; layer 3 -> rowdot ----
    for (int l = 0; l < 3; ++l) {
        float* rdl = (l == 2) ? rowdot : (float*)nullptr;
        agg_kernel<<<AGG_B, 256, 0, stream>>>(Hhi, rowptr, csr_src, Mb);
        gemm_kernel<<<GEMM_B, 512, 0, stream>>>(Mb, Hhi, Hlo,
                                                Wph + l * 32768, Wpl + l * 32768, bs[l],
                                                Hhi, Hlo, Wro, rdl);
    }

    // ---- per-graph sum + sigmoid ----
    final_kernel<<<N_GRAPHS, 64, 0, stream>>>(rowdot, batch, bro, out);
}